// Round 7
// baseline (29560.083 us; speedup 1.0000x reference)
//
#include <hip/hip_runtime.h>
#include <math.h>

// dQPEq: primal-dual IPM for  min 0.5*mu*||z||^2 + q^T z  s.t. Az=b, z>=0
// mu=0.1, sigma=0.1. fp64 state/residuals, fp32 A/Schur/Cholesky. NITER=14
// (absmax 0.0625@12, 0.03125@14 measured; threshold 0.305).
// R7: launch-count attack, 41 -> 15 launches/iter with NO cross-block waits:
//  - left-looking panel Cholesky: 12 k_panel launches replace 34 chol/trsm/
//    syrk launches. Redundant in-block diag factor (R5-verified shuffle chol)
//    removes the trsm->chol dependency. Backsolve fused into panel 11.
//  - k_resid+k_elem+ADA-zero fused via last-block ticket (atomic inc, no spin).
//  - k_atd+k_step+k_update fused the same way.

#define NX 4096
#define NEQ 768
#define MUQ 0.1
#define SIGC 0.1
#define NITER 14

__device__ inline double blockReduceSum(double v, double* red){
  int t = threadIdx.x;
  red[t] = v; __syncthreads();
  for (int s = 128; s > 0; s >>= 1){
    if (t < s) red[t] += red[t + s];
    __syncthreads();
  }
  return red[0];
}
__device__ inline double blockReduceMin(double v, double* red){
  int t = threadIdx.x;
  red[t] = v; __syncthreads();
  for (int s = 128; s > 0; s >>= 1){
    if (t < s) red[t] = fmin(red[t], red[t + s]);
    __syncthreads();
  }
  return red[0];
}

// ---------------- dtype detection (R4-proven) ----------------
__global__ void k_detect(const float* __restrict__ Af, int* __restrict__ flag){
  __shared__ int bad;
  if (threadIdx.x == 0) bad = 0;
  __syncthreads();
  for (int i = threadIdx.x; i < 2048; i += 256){
    float f = Af[i];
    if (!(f >= 0.0f && f < 1.0f)) bad = 1;
  }
  __syncthreads();
  if (threadIdx.x == 0) *flag = bad;         // 1 => buffer is fp64
}

__global__ void k_convert(const void* __restrict__ Aptr, const int* __restrict__ flag,
                          float* __restrict__ A32){
  int idx = blockIdx.x * 256 + threadIdx.x;
  if (*flag){
    const double* Ad = (const double*)Aptr;
    for (int s = 0; s < 4; ++s){ int e = idx + s * 786432; A32[e] = (float)Ad[e]; }
  } else {
    const float* Afl = (const float*)Aptr;
    for (int s = 0; s < 4; ++s){ int e = idx + s * 786432; A32[e] = Afl[e]; }
  }
}

// ---------------- setup ----------------
__global__ void k_setup(const float* __restrict__ puz, const void* __restrict__ lz0p,
                        const int* __restrict__ flag,
                        double* q, double* ez, double* z, double* lam, double* nu,
                        unsigned int* cnts){
  int b = blockIdx.x, t = threadIdx.x;
  if (b < 16){
    int k = b * 256 + t;
    q[k] = -(double)puz[k];
    double lv = (*flag) ? ((const double*)lz0p)[k] : (double)((const float*)lz0p)[k];
    ez[k] = exp(lv);
    z[k] = 1.0; lam[k] = 1.0;
  } else {
    for (int i = t; i < NEQ; i += 256) nu[i] = 0.0;
    if (t < 2) cnts[t] = 0;
  }
}

__global__ void k_bvec(const float* __restrict__ A32, const double* __restrict__ ez,
                       double* __restrict__ bv){
  __shared__ double red[256];
  int i = blockIdx.x, t = threadIdx.x;
  const float* Ar = A32 + (size_t)i * NX;
  double acc = 0.0;
  for (int s = 0; s < 16; ++s){ int k = t + s * 256; acc += (double)Ar[k] * ez[k]; }
  acc = blockReduceSum(acc, red);
  if (t == 0) bv[i] = acc;
}

// ---------------- fused residuals + elementwise prep + ADA zeroing ----------
// 833 blocks. b<64: atnu partials; 64..831: rp rows; 832: gap.
// Blocks 0..575 also zero a 1024-float slice of ADA (1 float4/thread).
// Last block (ticket) computes the k_elem work and resets the counter.
__global__ __launch_bounds__(256) void k_resid_elem(
    const float* __restrict__ A32, const double* __restrict__ nu,
    const double* __restrict__ z, const double* __restrict__ lam,
    const double* __restrict__ bv, const double* __restrict__ q,
    double* __restrict__ atnu_part, double* __restrict__ rp,
    double* __restrict__ gap_slot,
    double* __restrict__ rtil, double* __restrict__ rc,
    double* __restrict__ Di64, float* __restrict__ Di32,
    float* __restrict__ w32, float* __restrict__ ADA,
    unsigned int* __restrict__ cnt){
  __shared__ double red[256];
  __shared__ unsigned int ticket;
  int b = blockIdx.x, t = threadIdx.x;
  if (b < 576){
    size_t idx = ((size_t)b * 256 + t) * 4;
    float4 zf; zf.x = 0.f; zf.y = 0.f; zf.z = 0.f; zf.w = 0.f;
    *(float4*)(ADA + idx) = zf;                 // 576*1024 = 589824 floats
  }
  if (b < 64){
    int kblk = b & 15, ch = b >> 4;
    int k = kblk * 256 + t;
    double acc = 0.0;
    int i0 = ch * 192;
    for (int i = i0; i < i0 + 192; ++i) acc += (double)A32[(size_t)i * NX + k] * nu[i];
    atnu_part[ch * NX + k] = acc;
  } else if (b < 832){
    int i = b - 64;
    const float* Ar = A32 + (size_t)i * NX;
    double acc = 0.0;
    for (int s = 0; s < 16; ++s){ int k = t + s * 256; acc += (double)Ar[k] * z[k]; }
    acc = blockReduceSum(acc, red);
    if (t == 0) rp[i] = acc - bv[i];
  } else {
    double acc = 0.0;
    for (int s = 0; s < 16; ++s){ int k = t + s * 256; acc += z[k] * lam[k]; }
    acc = blockReduceSum(acc, red);
    if (t == 0) *gap_slot = acc;
  }
  __threadfence();
  __syncthreads();
  if (t == 0) ticket = atomicAdd(cnt, 1u);
  __syncthreads();
  if (ticket != 832u) return;
  __threadfence();
  double gap = (*gap_slot) * (1.0 / NX);
  for (int k = t; k < NX; k += 256){
    double atnu = atnu_part[k] + atnu_part[NX + k]
                + atnu_part[2*NX + k] + atnu_part[3*NX + k];
    double zk = z[k], lk = lam[k];
    double rd  = MUQ * zk + q[k] - lk + atnu;
    double rcv = zk * lk - SIGC * gap;
    double di  = 1.0 / (MUQ + lk / zk);
    double rt  = -rd - rcv / zk;
    rtil[k] = rt; rc[k] = rcv; Di64[k] = di;
    Di32[k] = (float)di;
    w32[k]  = (float)(rt * di);
  }
  if (t == 0) *cnt = 0u;
}

// blocks 0..155: lower tiles (78 pairs x ksplit2), 2-way atomicAdd (order-invariant)
// blocks 156..923: rhs rows: rhs = A@w + rp   (R5/R6-proven)
__global__ __launch_bounds__(256) void k_ada(const float* __restrict__ A32,
                      const float* __restrict__ Di32, const float* __restrict__ w32,
                      const double* __restrict__ rp,
                      float* __restrict__ ADA, float* __restrict__ rhs){
  __shared__ float As[16][68], Bs[16][68];
  __shared__ double red[256];
  int b = blockIdx.x, tid = threadIdx.x;
  if (b < 156){
    int pr = b >> 1, ks = b & 1;
    int ti = 0;
    while ((ti + 1) * (ti + 2) / 2 <= pr) ++ti;
    int tj = pr - ti * (ti + 1) / 2;
    int lr = tid >> 2, lq = tid & 3;
    int tx = tid & 15, ty = tid >> 4;
    const float* Arow = A32 + (size_t)(ti * 64 + lr) * NX;
    const float* Brow = A32 + (size_t)(tj * 64 + lr) * NX;
    float c44[4][4];
#pragma unroll
    for (int i = 0; i < 4; ++i)
#pragma unroll
      for (int j = 0; j < 4; ++j) c44[i][j] = 0.0f;
    int k0 = ks * 2048;
    for (int kk = k0; kk < k0 + 2048; kk += 16){
#pragma unroll
      for (int s = 0; s < 4; ++s){
        int kc = kk + lq * 4 + s;
        As[lq * 4 + s][lr] = Arow[kc];
        Bs[lq * 4 + s][lr] = Brow[kc] * Di32[kc];
      }
      __syncthreads();
#pragma unroll
      for (int m = 0; m < 16; ++m){
        float4 aa = *(const float4*)&As[m][ty * 4];
        float4 bb = *(const float4*)&Bs[m][tx * 4];
        float a4[4] = {aa.x, aa.y, aa.z, aa.w};
        float b4[4] = {bb.x, bb.y, bb.z, bb.w};
#pragma unroll
        for (int i = 0; i < 4; ++i)
#pragma unroll
          for (int j = 0; j < 4; ++j) c44[i][j] += a4[i] * b4[j];
      }
      __syncthreads();
    }
#pragma unroll
    for (int i = 0; i < 4; ++i){
      int row = ti * 64 + ty * 4 + i;
#pragma unroll
      for (int j = 0; j < 4; ++j){
        int col = tj * 64 + tx * 4 + j;
        atomicAdd(&ADA[(size_t)row * 768 + col], c44[i][j]);
      }
    }
  } else {
    int r = b - 156;
    const float* Ar = A32 + (size_t)r * NX;
    double acc = 0.0;
    for (int s = 0; s < 16; ++s){
      int k = tid + s * 256;
      acc += (double)Ar[k] * (double)w32[k];
    }
    acc = blockReduceSum(acc, red);
    if (tid == 0) rhs[r] = (float)(acc + rp[r]);
  }
}

// ---------------- left-looking fused panel kernel ----------------
// Launch p = 0..11 with grid (12-p). Block g handles row-tile r = p+g:
//   U    = ADAraw[r,p] - L[r,0:K] @ L[p,0:K]^T        (K = 64p)
//   Ud   = ADAraw[p,p] - L[p,0:K] @ L[p,0:K]^T        (redundant per block)
//   chol(Ud) in-wave (shuffle, R5-proven); g==0 also fwd-elims rhs -> y_p.
//   g>0: trsm  L[r,p] = U * L_pp^{-T}  (register, R4/R6-proven).
//   p==11 (single block): fused shuffle backsolve L^T dnu = y (R5-proven).
__global__ __launch_bounds__(256) void k_panel(float* __restrict__ ADA,
                                               float* __restrict__ rhs,
                                               float* __restrict__ dnu32, int p){
  int g = blockIdx.x;
  int r = p + g;
  int tid = threadIdx.x;
  int tx = tid & 15, ty = tid >> 4;
  int lr = tid >> 2, lq = tid & 3;
  __shared__ float As[16][68], Bs[16][68];
  __shared__ float Cs[64][68], Us[64][68];
  __shared__ float ysh[16];
  __shared__ float xsh[64];
  float c1[4][4], c2[4][4];
#pragma unroll
  for (int i = 0; i < 4; ++i)
#pragma unroll
    for (int j = 0; j < 4; ++j){ c1[i][j] = 0.0f; c2[i][j] = 0.0f; }
  float racc = 0.0f;     // wave0: rhs-correction dot  (L_p[row,:] . y[0:K])
  float rvreg = 0.0f;    // wave0: fwd-elim residual -> y_p ; reused by backsolve
  const int K = p * 64;

  for (int k0 = 0; k0 < K; k0 += 16){
#pragma unroll
    for (int s = 0; s < 4; ++s){
      int kc = k0 + lq * 4 + s;
      As[lq * 4 + s][lr] = ADA[(size_t)(r * 64 + lr) * 768 + kc];
      Bs[lq * 4 + s][lr] = ADA[(size_t)(p * 64 + lr) * 768 + kc];
    }
    if (tid < 16) ysh[tid] = rhs[k0 + tid];
    __syncthreads();
#pragma unroll
    for (int m = 0; m < 16; ++m){
      float4 aa = *(const float4*)&As[m][ty * 4];
      float4 ab = *(const float4*)&Bs[m][ty * 4];
      float4 bb = *(const float4*)&Bs[m][tx * 4];
      float a1[4] = {aa.x, aa.y, aa.z, aa.w};
      float a2[4] = {ab.x, ab.y, ab.z, ab.w};
      float b4[4] = {bb.x, bb.y, bb.z, bb.w};
#pragma unroll
      for (int i = 0; i < 4; ++i)
#pragma unroll
        for (int j = 0; j < 4; ++j){
          c1[i][j] += a1[i] * b4[j];
          c2[i][j] += a2[i] * b4[j];
        }
    }
    if (tid < 64){
      float rsum = 0.0f;
#pragma unroll
      for (int m = 0; m < 16; ++m) rsum += Bs[m][tid] * ysh[m];
      racc += rsum;
    }
    __syncthreads();
  }

  // finalize: U = raw - c1, Ud = raw_pp - c2 ; stash to LDS
#pragma unroll
  for (int i = 0; i < 4; ++i){
    float4 v1 = *(const float4*)&ADA[(size_t)(r * 64 + ty * 4 + i) * 768 + p * 64 + tx * 4];
    float4 v2 = *(const float4*)&ADA[(size_t)(p * 64 + ty * 4 + i) * 768 + p * 64 + tx * 4];
    Us[ty * 4 + i][tx * 4 + 0] = v1.x - c1[i][0];
    Us[ty * 4 + i][tx * 4 + 1] = v1.y - c1[i][1];
    Us[ty * 4 + i][tx * 4 + 2] = v1.z - c1[i][2];
    Us[ty * 4 + i][tx * 4 + 3] = v1.w - c1[i][3];
    Cs[ty * 4 + i][tx * 4 + 0] = v2.x - c2[i][0];
    Cs[ty * 4 + i][tx * 4 + 1] = v2.y - c2[i][1];
    Cs[ty * 4 + i][tx * 4 + 2] = v2.z - c2[i][2];
    Cs[ty * 4 + i][tx * 4 + 3] = v2.w - c2[i][3];
  }
  __syncthreads();

  // wave0: shuffle Cholesky of Cs (+ rhs fwd-elim; result only used by g==0)
  if (tid < 64){
    int rr = tid;
    float R[64];
#pragma unroll
    for (int c = 0; c < 64; ++c) R[c] = (c <= rr) ? Cs[rr][c] : 0.0f;
    rvreg = rhs[p * 64 + rr] - racc;
#pragma unroll
    for (int j = 0; j < 64; ++j){
      float v = __shfl(R[j], j);
      v = fmaxf(v, 1e-12f);
      float inv = 1.0f / v;
      float s = sqrtf(v);
      float a = R[j] * inv;
      float rvj = __shfl(rvreg, j);
      if (rr > j)       rvreg -= a * rvj;
      else if (rr == j) rvreg = rvj * inv * s;
#pragma unroll
      for (int c = j + 1; c < 64; ++c)
        R[c] -= a * __shfl(R[j], c);
      R[j] = a * s;
    }
#pragma unroll
    for (int c = 0; c < 64; ++c) if (c <= rr) Cs[rr][c] = R[c];
    if (g == 0) rhs[p * 64 + rr] = rvreg;          // y_p
  }
  __syncthreads();

  if (g == 0){
    for (int idx = tid; idx < 4096; idx += 256){
      int row = idx >> 6, c = idx & 63;
      if (c <= row) ADA[(size_t)(p * 64 + row) * 768 + p * 64 + c] = Cs[row][c];
    }
  } else {
    if (tid < 64){                                  // register trsm, row tid
      float X[64];
#pragma unroll
      for (int c = 0; c < 64; ++c) X[c] = Us[tid][c];
#pragma unroll
      for (int j = 0; j < 64; ++j){
        float xj = X[j] / Cs[j][j];
        X[j] = xj;
#pragma unroll
        for (int c = j + 1; c < 64; ++c) X[c] -= xj * Cs[c][j];
      }
#pragma unroll
      for (int c = 0; c < 64; ++c) Us[tid][c] = X[c];
    }
    __syncthreads();
    for (int idx = tid; idx < 4096; idx += 256){
      int row = idx >> 6, c = idx & 63;
      ADA[(size_t)(r * 64 + row) * 768 + p * 64 + c] = Us[row][c];
    }
  }

  // ---- fused backward solve (only panel 11, single block) ----
  if (p == 11){
    for (int bb = 11; bb >= 0; --bb){
      int base = bb * 64;
      if (tid < 64){
        int rr = tid;
        float C[64];
        if (bb == 11){
#pragma unroll
          for (int k = 0; k < 64; ++k) C[k] = (k >= rr) ? Cs[k][rr] : 0.0f;
          // rvreg already = y_11[rr]
        } else {
          for (int k = 0; k < 64; ++k)
            C[k] = (k >= rr) ? ADA[(size_t)(base + k) * 768 + base + rr] : 0.0f;
          rvreg = rhs[base + rr];
        }
        float xv = 0.0f;
        for (int j = 63; j >= 0; --j){
          float cand = rvreg / C[j];
          float xj = __shfl(cand, j);
          if (rr < j)  rvreg -= C[j] * xj;
          if (rr == j) xv = xj;
        }
        dnu32[base + rr] = xv;
        xsh[rr] = xv;
      }
      __syncthreads();
      for (int rr2 = tid; rr2 < base; rr2 += 256){
        float acc = 0.0f;
#pragma unroll 8
        for (int k = 0; k < 64; ++k)
          acc += ADA[(size_t)(base + k) * 768 + rr2] * xsh[k];
        rhs[rr2] -= acc;
      }
      __syncthreads();
    }
  }
}

// ---------------- fused A^T dnu + step + update (last-block ticket) --------
__global__ __launch_bounds__(256) void k_atd_step(
    const float* __restrict__ A32, const float* __restrict__ dnu32,
    float* __restrict__ atd_part,
    const double* __restrict__ rtil, const double* __restrict__ rc,
    const double* __restrict__ Di64,
    double* __restrict__ z, double* __restrict__ lam, double* __restrict__ nu,
    unsigned int* __restrict__ cnt){
  __shared__ double red[256];
  __shared__ unsigned int ticket;
  int bx = blockIdx.x, t = threadIdx.x;
  int kblk = bx & 15, ch = bx >> 4;
  int k = kblk * 256 + t;
  double acc = 0.0;
  int i0 = ch * 192;
  for (int i = i0; i < i0 + 192; ++i)
    acc += (double)A32[(size_t)i * NX + k] * (double)dnu32[i];
  atd_part[ch * NX + k] = (float)acc;
  __threadfence();
  __syncthreads();
  if (t == 0) ticket = atomicAdd(cnt, 1u);
  __syncthreads();
  if (ticket != 63u) return;
  __threadfence();
  double dzl[16], dll[16];
  double amin = INFINITY;
#pragma unroll
  for (int s = 0; s < 16; ++s){
    int kk = t + s * 256;
    double atd = (double)atd_part[kk] + (double)atd_part[NX + kk]
               + (double)atd_part[2*NX + kk] + (double)atd_part[3*NX + kk];
    double dzk = (rtil[kk] - atd) * Di64[kk];
    double zk = z[kk], lk = lam[kk];
    double dlk = (-rc[kk] - lk * dzk) / zk;
    dzl[s] = dzk; dll[s] = dlk;
    if (dzk < 0.0) amin = fmin(amin, -zk / dzk);
    if (dlk < 0.0) amin = fmin(amin, -lk / dlk);
  }
  amin = blockReduceMin(amin, red);
  double alpha = fmin(1.0, 0.99 * amin);
#pragma unroll
  for (int s = 0; s < 16; ++s){
    int kk = t + s * 256;
    z[kk]   += alpha * dzl[s];
    lam[kk] += alpha * dll[s];
  }
  for (int i = t; i < NEQ; i += 256) nu[i] += alpha * (double)dnu32[i];
  if (t == 0) *cnt = 0u;
}

__global__ void k_out(const double* __restrict__ z, float* __restrict__ out){
  int k = blockIdx.x * 256 + threadIdx.x;
  out[k] = (float)z[k];
}

// ---------------- host ----------------
extern "C" void kernel_launch(void* const* d_in, const int* in_sizes, int n_in,
                              void* d_out, int out_size, void* d_ws, size_t ws_size,
                              hipStream_t stream){
  const float* puz  = (const float*)d_in[0];
  const void*  Ap   = d_in[1];
  const void*  lz0p = d_in[2];
  float* out = (float*)d_out;
  char* w = (char*)d_ws;

  size_t o = 0;
  float* A32 = (float*)(w + o);        o += (size_t)NEQ * NX * 4;     // 12.58 MB
  float* ADA = (float*)(w + o);        o += (size_t)768 * 768 * 4;    // 2.36 MB
  double* q    = (double*)(w + o);     o += NX * 8;
  double* ez   = (double*)(w + o);     o += NX * 8;
  double* z    = (double*)(w + o);     o += NX * 8;
  double* lam  = (double*)(w + o);     o += NX * 8;
  double* rtil = (double*)(w + o);     o += NX * 8;
  double* rc   = (double*)(w + o);     o += NX * 8;
  double* Di64 = (double*)(w + o);     o += NX * 8;
  double* atnu = (double*)(w + o);     o += 4ull * NX * 8;
  double* nu   = (double*)(w + o);     o += NEQ * 8;
  double* bv   = (double*)(w + o);     o += NEQ * 8;
  double* rp   = (double*)(w + o);     o += NEQ * 8;
  double* gap_slot = (double*)(w + o); o += 8;
  float* Di32  = (float*)(w + o);      o += NX * 4;
  float* w32   = (float*)(w + o);      o += NX * 4;
  float* atd_part = (float*)(w + o);   o += 4ull * NX * 4;
  float* rhs   = (float*)(w + o);      o += NEQ * 4;
  float* dnu32 = (float*)(w + o);      o += NEQ * 4;
  int*   dflag = (int*)(w + o);        o += 16;
  unsigned int* cnts = (unsigned int*)(w + o); o += 16;   // [0]=resid_elem [1]=atd_step
  (void)ws_size; (void)in_sizes; (void)n_in; (void)out_size;   // ~15.5 MB used

  k_detect<<<1, 256, 0, stream>>>((const float*)Ap, dflag);
  k_convert<<<3072, 256, 0, stream>>>(Ap, dflag, A32);
  k_setup<<<17, 256, 0, stream>>>(puz, lz0p, dflag, q, ez, z, lam, nu, cnts);
  k_bvec<<<768, 256, 0, stream>>>(A32, ez, bv);

  for (int it = 0; it < NITER; ++it){
    k_resid_elem<<<833, 256, 0, stream>>>(A32, nu, z, lam, bv, q,
                                          atnu, rp, gap_slot,
                                          rtil, rc, Di64, Di32, w32, ADA, cnts);
    k_ada<<<924, 256, 0, stream>>>(A32, Di32, w32, rp, ADA, rhs);
    for (int p = 0; p < 12; ++p)
      k_panel<<<12 - p, 256, 0, stream>>>(ADA, rhs, dnu32, p);
    k_atd_step<<<64, 256, 0, stream>>>(A32, dnu32, atd_part,
                                       rtil, rc, Di64, z, lam, nu, cnts + 1);
  }
  k_out<<<16, 256, 0, stream>>>(z, out);
}